// Round 1
// baseline (47.785 us; speedup 1.0000x reference)
//
#include <hip/hip_runtime.h>
#include <math.h>

#define B_ 64
#define S_ 24
#define E_ 128
#define G_ 256
#define N_ (B_ * S_)      // 1536
#define Km_ 100
#define Kch_ 200
#define Ko_ 50
#define Kp_ 50
#define Kc_ 30
#define TOTK_ 435         // 100+200+50+50+1+30+4

#define Vm_ 1000
#define Vch_ 3000
#define Vo_ 500
#define Vp_ 1500
#define Vl_ 700
#define Vc_ 2000
#define Vgen_ 2
#define Veth_ 10
#define Vins_ 5
#define Vage_ 100
#define TOTROWS_ 8817     // sum of all table rows

// rowmean buffer segment offsets (in floats)
#define OFF_MED 0
#define OFF_CHART 1000
#define OFF_OUT 4000
#define OFF_PROC 4500
#define OFF_LAB 6000
#define OFF_COND 6700
#define OFF_GEN 8700
#define OFF_ETH 8702
#define OFF_INS 8712
#define OFF_AGE 8717
#define OFF_MACC 8817     // macc[435] follows rowmeans in d_ws

// ---------------------------------------------------------------------------
// Kernel A: one wave (64 lanes) per embedding row -> rowmean = mean over E=128
// ---------------------------------------------------------------------------
__global__ __launch_bounds__(256) void rowmeans_kernel(
    const float* __restrict__ medE, const float* __restrict__ chartE,
    const float* __restrict__ outE, const float* __restrict__ procE,
    const float* __restrict__ labE, const float* __restrict__ condE,
    const float* __restrict__ genE, const float* __restrict__ ethE,
    const float* __restrict__ insE, const float* __restrict__ ageE,
    float* __restrict__ rm)
{
    int wave = (blockIdx.x * blockDim.x + threadIdx.x) >> 6;
    int lane = threadIdx.x & 63;
    if (wave >= TOTROWS_) return;

    const float* src;
    int r = wave;
    if (r < Vm_)                  { src = medE; }
    else if ((r -= Vm_)  < Vch_)  { src = chartE; }
    else if ((r -= Vch_) < Vo_)   { src = outE; }
    else if ((r -= Vo_)  < Vp_)   { src = procE; }
    else if ((r -= Vp_)  < Vl_)   { src = labE; }
    else if ((r -= Vl_)  < Vc_)   { src = condE; }
    else if ((r -= Vc_)  < Vgen_) { src = genE; }
    else if ((r -= Vgen_)< Veth_) { src = ethE; }
    else if ((r -= Veth_)< Vins_) { src = insE; }
    else                          { r -= Vins_; src = ageE; }

    float2 v = *reinterpret_cast<const float2*>(src + (size_t)r * E_ + lane * 2);
    float s = v.x + v.y;
    #pragma unroll
    for (int off = 32; off > 0; off >>= 1) s += __shfl_down(s, off, 64);
    if (lane == 0) rm[wave] = s * (1.0f / E_);
}

// ---------------------------------------------------------------------------
// Kernel B: one block per output column c in [0, 435): deterministic
// gather-sum of rowmeans over the N (or B) samples -> macc[c]
// ---------------------------------------------------------------------------
__device__ __forceinline__ int clampi(int v, int hi) {
    return v < 0 ? 0 : (v > hi ? hi : v);
}

__global__ __launch_bounds__(256) void colsum_kernel(
    const int* __restrict__ meds, const int* __restrict__ chart,
    const int* __restrict__ outv, const int* __restrict__ proc,
    const int* __restrict__ lab,  const int* __restrict__ conds,
    const int* __restrict__ demo,
    const float* __restrict__ rm, float* __restrict__ macc)
{
    const int c = blockIdx.x;
    const int t = threadIdx.x;
    float s = 0.0f;
    float scale;

    if (c < 400) {
        const int* idx; int K, kk, base, vmax;
        if (c < Km_)             { idx = meds;  K = Km_;  kk = c;        base = OFF_MED;  vmax = Vm_ - 1; }
        else if (c < 300)        { idx = chart; K = Kch_; kk = c - 100;  base = OFF_CHART;vmax = Vch_ - 1; }
        else if (c < 350)        { idx = outv;  K = Ko_;  kk = c - 300;  base = OFF_OUT;  vmax = Vo_ - 1; }
        else                     { idx = proc;  K = Kp_;  kk = c - 350;  base = OFF_PROC; vmax = Vp_ - 1; }
        for (int n = t; n < N_; n += 256)
            s += rm[base + clampi(idx[n * K + kk], vmax)];
        scale = 1.0f / N_;
    } else if (c == 400) {
        for (int n = t; n < N_; n += 256)
            s += rm[OFF_LAB + clampi(lab[n], Vl_ - 1)];
        scale = 1.0f / N_;
    } else if (c < 431) {
        int kk = c - 401;
        for (int b = t; b < B_; b += 256)
            s += rm[OFF_COND + clampi(conds[b * Kc_ + kk], Vc_ - 1)];
        scale = 1.0f / B_;
    } else {
        int j = c - 431;
        int base = (j == 0) ? OFF_GEN : (j == 1) ? OFF_ETH : (j == 2) ? OFF_INS : OFF_AGE;
        for (int b = t; b < B_; b += 256)
            s += rm[base + demo[b * 4 + j]];
        scale = 1.0f / B_;
    }

    __shared__ float red[256];
    red[t] = s;
    __syncthreads();
    #pragma unroll
    for (int off = 128; off > 0; off >>= 1) {
        if (t < off) red[t] += red[t + off];
        __syncthreads();
    }
    if (t == 0) macc[c] = red[0] * scale;
}

// ---------------------------------------------------------------------------
// Kernel C: one block runs the whole MLP head (all rows identical after the
// axis-0 mean, entropy weight cancels to exactly 1/N).
// ---------------------------------------------------------------------------
__global__ __launch_bounds__(256) void head_kernel(
    const float* __restrict__ macc,
    const float* __restrict__ projW, const float* __restrict__ projb,
    const float* __restrict__ W1, const float* __restrict__ b1,
    const float* __restrict__ W2, const float* __restrict__ b2,
    const float* __restrict__ fc1W, const float* __restrict__ fc1b,
    const float* __restrict__ fc2W, const float* __restrict__ fc2b,
    float* __restrict__ outp)
{
    __shared__ float sm[TOTK_];
    __shared__ float xbar[E_];
    __shared__ float h1[G_];
    __shared__ float h2[G_];
    __shared__ float f[G_ / 2];
    __shared__ float red[64];

    const int t = threadIdx.x;

    for (int i = t; i < TOTK_; i += 256) sm[i] = macc[i];
    __syncthreads();

    // xbar[e] = sum_k macc[k] * proj_W[k,e] + proj_b[e]
    if (t < E_) {
        float acc = projb[t];
        for (int k = 0; k < TOTK_; ++k) acc += sm[k] * projW[k * E_ + t];
        xbar[t] = acc;
    }
    __syncthreads();

    // h1[g] = relu(xbar @ W1 + b1) * (1/N)   (entropy weight == 1/N exactly)
    {
        float acc = b1[t];
        #pragma unroll 4
        for (int e = 0; e < E_; ++e) acc += xbar[e] * W1[e * G_ + t];
        h1[t] = fmaxf(acc, 0.0f) * (1.0f / N_);
    }
    __syncthreads();

    // h2[g] = h1 @ W2 + b2
    {
        float acc = b2[t];
        #pragma unroll 4
        for (int g = 0; g < G_; ++g) acc += h1[g] * W2[g * G_ + t];
        h2[t] = acc;
    }
    __syncthreads();

    // f[j] = relu(h2 @ fc1_W + fc1_b)
    if (t < G_ / 2) {
        float acc = fc1b[t];
        #pragma unroll 4
        for (int g = 0; g < G_; ++g) acc += h2[g] * fc1W[g * (G_ / 2) + t];
        f[t] = fmaxf(acc, 0.0f);
    }
    __syncthreads();

    // o = f . fc2_W + fc2_b  (reduce across block)
    float p = (t < G_ / 2) ? f[t] * fc2W[t] : 0.0f;
    #pragma unroll
    for (int off = 32; off > 0; off >>= 1) p += __shfl_down(p, off, 64);
    if ((t & 63) == 0) red[t >> 6] = p;
    __syncthreads();
    if (t == 0) red[0] = red[0] + red[1] + red[2] + red[3] + fc2b[0];
    __syncthreads();

    const float o = red[0];
    const float sig = 1.0f / (1.0f + expf(-o));
    if (t < B_)            outp[t] = sig;       // output 0: sigmoid(o)
    else if (t < 2 * B_)   outp[t] = o;         // output 1: o
}

// ---------------------------------------------------------------------------
extern "C" void kernel_launch(void* const* d_in, const int* in_sizes, int n_in,
                              void* d_out, int out_size, void* d_ws, size_t ws_size,
                              hipStream_t stream) {
    const int* meds  = (const int*)d_in[0];
    const int* chart = (const int*)d_in[1];
    const int* outv  = (const int*)d_in[2];
    const int* proc  = (const int*)d_in[3];
    const int* lab   = (const int*)d_in[4];
    const int* conds = (const int*)d_in[5];
    const int* demo  = (const int*)d_in[6];
    const float* medE   = (const float*)d_in[7];
    const float* chartE = (const float*)d_in[8];
    const float* outE   = (const float*)d_in[9];
    const float* procE  = (const float*)d_in[10];
    const float* labE   = (const float*)d_in[11];
    const float* condE  = (const float*)d_in[12];
    const float* genE   = (const float*)d_in[13];
    const float* ethE   = (const float*)d_in[14];
    const float* insE   = (const float*)d_in[15];
    const float* ageE   = (const float*)d_in[16];
    const float* projW  = (const float*)d_in[17];
    const float* projb  = (const float*)d_in[18];
    const float* W1     = (const float*)d_in[19];
    const float* b1     = (const float*)d_in[20];
    const float* W2     = (const float*)d_in[21];
    const float* b2     = (const float*)d_in[22];
    const float* fc1W   = (const float*)d_in[23];
    const float* fc1b   = (const float*)d_in[24];
    const float* fc2W   = (const float*)d_in[25];
    const float* fc2b   = (const float*)d_in[26];

    float* rm   = (float*)d_ws;          // 8817 floats
    float* macc = rm + OFF_MACC;         // 435 floats
    float* outp = (float*)d_out;         // 128 floats

    // A: row means — one wave per row, 4 waves/block
    int blocksA = (TOTROWS_ + 3) / 4;
    rowmeans_kernel<<<blocksA, 256, 0, stream>>>(
        medE, chartE, outE, procE, labE, condE, genE, ethE, insE, ageE, rm);

    // B: column gather-sums — one block per column
    colsum_kernel<<<TOTK_, 256, 0, stream>>>(
        meds, chart, outv, proc, lab, conds, demo, rm, macc);

    // C: MLP head — single block
    head_kernel<<<1, 256, 0, stream>>>(
        macc, projW, projb, W1, b1, W2, b2, fc1W, fc1b, fc2W, fc2b, outp);
}

// Round 2
// 31.055 us; speedup vs baseline: 1.5387x; 1.5387x over previous
//
#include <hip/hip_runtime.h>
#include <math.h>

#define B_ 64
#define S_ 24
#define E_ 128
#define G_ 256
#define N_ (B_ * S_)      // 1536
#define Km_ 100
#define Kch_ 200
#define Ko_ 50
#define Kp_ 50
#define Kc_ 30
#define TOTK_ 435         // 100+200+50+50+1+30+4

#define Vm_ 1000
#define Vch_ 3000
#define Vo_ 500
#define Vp_ 1500
#define Vl_ 700
#define Vc_ 2000
#define Vgen_ 2
#define Veth_ 10
#define Vins_ 5
#define Vage_ 100
#define TOTROWS_ 8817     // sum of all table rows

// rowmean buffer segment offsets (in floats)
#define OFF_MED 0
#define OFF_CHART 1000
#define OFF_OUT 4000
#define OFF_PROC 4500
#define OFF_LAB 6000
#define OFF_COND 6700
#define OFF_GEN 8700
#define OFF_ETH 8702
#define OFF_INS 8712
#define OFF_AGE 8717
#define OFF_MACC 8817     // macc[435] follows rowmeans in d_ws

// ---------------------------------------------------------------------------
// Kernel A: one wave (64 lanes) per embedding row -> rowmean = mean over E=128
// ---------------------------------------------------------------------------
__global__ __launch_bounds__(256) void rowmeans_kernel(
    const float* __restrict__ medE, const float* __restrict__ chartE,
    const float* __restrict__ outE, const float* __restrict__ procE,
    const float* __restrict__ labE, const float* __restrict__ condE,
    const float* __restrict__ genE, const float* __restrict__ ethE,
    const float* __restrict__ insE, const float* __restrict__ ageE,
    float* __restrict__ rm)
{
    int wave = (blockIdx.x * blockDim.x + threadIdx.x) >> 6;
    int lane = threadIdx.x & 63;
    if (wave >= TOTROWS_) return;

    const float* src;
    int r = wave;
    if (r < Vm_)                  { src = medE; }
    else if ((r -= Vm_)  < Vch_)  { src = chartE; }
    else if ((r -= Vch_) < Vo_)   { src = outE; }
    else if ((r -= Vo_)  < Vp_)   { src = procE; }
    else if ((r -= Vp_)  < Vl_)   { src = labE; }
    else if ((r -= Vl_)  < Vc_)   { src = condE; }
    else if ((r -= Vc_)  < Vgen_) { src = genE; }
    else if ((r -= Vgen_)< Veth_) { src = ethE; }
    else if ((r -= Veth_)< Vins_) { src = insE; }
    else                          { r -= Vins_; src = ageE; }

    float2 v = *reinterpret_cast<const float2*>(src + (size_t)r * E_ + lane * 2);
    float s = v.x + v.y;
    #pragma unroll
    for (int off = 32; off > 0; off >>= 1) s += __shfl_down(s, off, 64);
    if (lane == 0) rm[wave] = s * (1.0f / E_);
}

// ---------------------------------------------------------------------------
// Kernel B: one block per output column c in [0, 435): deterministic
// gather-sum of rowmeans over the N (or B) samples -> macc[c]
// ---------------------------------------------------------------------------
__device__ __forceinline__ int clampi(int v, int hi) {
    return v < 0 ? 0 : (v > hi ? hi : v);
}

__global__ __launch_bounds__(256) void colsum_kernel(
    const int* __restrict__ meds, const int* __restrict__ chart,
    const int* __restrict__ outv, const int* __restrict__ proc,
    const int* __restrict__ lab,  const int* __restrict__ conds,
    const int* __restrict__ demo,
    const float* __restrict__ rm, float* __restrict__ macc)
{
    const int c = blockIdx.x;
    const int t = threadIdx.x;
    float s = 0.0f;
    float scale;

    if (c < 400) {
        const int* idx; int K, kk, base, vmax;
        if (c < Km_)             { idx = meds;  K = Km_;  kk = c;        base = OFF_MED;  vmax = Vm_ - 1; }
        else if (c < 300)        { idx = chart; K = Kch_; kk = c - 100;  base = OFF_CHART;vmax = Vch_ - 1; }
        else if (c < 350)        { idx = outv;  K = Ko_;  kk = c - 300;  base = OFF_OUT;  vmax = Vo_ - 1; }
        else                     { idx = proc;  K = Kp_;  kk = c - 350;  base = OFF_PROC; vmax = Vp_ - 1; }
        for (int n = t; n < N_; n += 256)
            s += rm[base + clampi(idx[n * K + kk], vmax)];
        scale = 1.0f / N_;
    } else if (c == 400) {
        for (int n = t; n < N_; n += 256)
            s += rm[OFF_LAB + clampi(lab[n], Vl_ - 1)];
        scale = 1.0f / N_;
    } else if (c < 431) {
        int kk = c - 401;
        for (int b = t; b < B_; b += 256)
            s += rm[OFF_COND + clampi(conds[b * Kc_ + kk], Vc_ - 1)];
        scale = 1.0f / B_;
    } else {
        int j = c - 431;
        int base = (j == 0) ? OFF_GEN : (j == 1) ? OFF_ETH : (j == 2) ? OFF_INS : OFF_AGE;
        for (int b = t; b < B_; b += 256)
            s += rm[base + demo[b * 4 + j]];
        scale = 1.0f / B_;
    }

    __shared__ float red[256];
    red[t] = s;
    __syncthreads();
    #pragma unroll
    for (int off = 128; off > 0; off >>= 1) {
        if (t < off) red[t] += red[t + off];
        __syncthreads();
    }
    if (t == 0) macc[c] = red[0] * scale;
}

// ---------------------------------------------------------------------------
// Kernel C: single block, 512 threads (8 waves). Every GEMV stage is k-split
// 8 ways across wave-groups with float2/float4 vector loads + LDS reduce, so
// the whole chain is ~17 L2-latency rounds instead of ~100.
// Entropy weight over identical rows == exactly 1/N (cancels).
// ---------------------------------------------------------------------------
__global__ __launch_bounds__(512) void head_kernel(
    const float* __restrict__ macc,
    const float* __restrict__ projW, const float* __restrict__ projb,
    const float* __restrict__ W1, const float* __restrict__ b1,
    const float* __restrict__ W2, const float* __restrict__ b2,
    const float* __restrict__ fc1W, const float* __restrict__ fc1b,
    const float* __restrict__ fc2W, const float* __restrict__ fc2b,
    float* __restrict__ outp)
{
    __shared__ float sm[TOTK_];
    __shared__ float xbar[E_];
    __shared__ float h1s[G_];
    __shared__ float h2s[G_];
    __shared__ float fsh[G_ / 2];
    __shared__ float4 part4[8][64];
    __shared__ float2 part2[8][64];
    __shared__ float red[8];
    __shared__ float oval;

    const int t = threadIdx.x;
    const int lane = t & 63;
    const int oc = t >> 6;      // wave-group 0..7

    for (int i = t; i < TOTK_; i += 512) sm[i] = macc[i];
    __syncthreads();

    // ---- xbar[128] = sm[435] @ projW[435,128] + projb : float2, 8-way k-split
    {
        const float2* Wp = (const float2*)projW;   // [435][64]
        const int k0 = (TOTK_ * oc) >> 3;
        const int k1 = (TOTK_ * (oc + 1)) >> 3;
        float2 acc = {0.f, 0.f};
        #pragma unroll 8
        for (int k = k0; k < k1; ++k) {
            float s = sm[k];
            float2 w = Wp[k * 64 + lane];
            acc.x += s * w.x; acc.y += s * w.y;
        }
        part2[oc][lane] = acc;
        __syncthreads();
        if (t < 64) {
            float2 a = part2[0][t];
            #pragma unroll
            for (int j = 1; j < 8; ++j) { a.x += part2[j][t].x; a.y += part2[j][t].y; }
            xbar[2 * t]     = a.x + projb[2 * t];
            xbar[2 * t + 1] = a.y + projb[2 * t + 1];
        }
        __syncthreads();
    }

    // ---- h1[256] = relu(xbar @ W1[128,256] + b1) * (1/N) : float4, 8-way
    {
        const float4* Wp = (const float4*)W1;      // [128][64]
        const int k0 = oc * 16, k1 = k0 + 16;
        float4 acc = {0.f, 0.f, 0.f, 0.f};
        #pragma unroll 8
        for (int k = k0; k < k1; ++k) {
            float s = xbar[k];
            float4 w = Wp[k * 64 + lane];
            acc.x += s * w.x; acc.y += s * w.y; acc.z += s * w.z; acc.w += s * w.w;
        }
        part4[oc][lane] = acc;
        __syncthreads();
        if (t < 64) {
            float4 a = part4[0][t];
            #pragma unroll
            for (int j = 1; j < 8; ++j) {
                float4 p = part4[j][t];
                a.x += p.x; a.y += p.y; a.z += p.z; a.w += p.w;
            }
            float4 bb = ((const float4*)b1)[t];
            h1s[4 * t]     = fmaxf(a.x + bb.x, 0.f) * (1.0f / N_);
            h1s[4 * t + 1] = fmaxf(a.y + bb.y, 0.f) * (1.0f / N_);
            h1s[4 * t + 2] = fmaxf(a.z + bb.z, 0.f) * (1.0f / N_);
            h1s[4 * t + 3] = fmaxf(a.w + bb.w, 0.f) * (1.0f / N_);
        }
        __syncthreads();
    }

    // ---- h2[256] = h1 @ W2[256,256] + b2 : float4, 8-way
    {
        const float4* Wp = (const float4*)W2;      // [256][64]
        const int k0 = oc * 32, k1 = k0 + 32;
        float4 acc = {0.f, 0.f, 0.f, 0.f};
        #pragma unroll 8
        for (int k = k0; k < k1; ++k) {
            float s = h1s[k];
            float4 w = Wp[k * 64 + lane];
            acc.x += s * w.x; acc.y += s * w.y; acc.z += s * w.z; acc.w += s * w.w;
        }
        part4[oc][lane] = acc;
        __syncthreads();
        if (t < 64) {
            float4 a = part4[0][t];
            #pragma unroll
            for (int j = 1; j < 8; ++j) {
                float4 p = part4[j][t];
                a.x += p.x; a.y += p.y; a.z += p.z; a.w += p.w;
            }
            float4 bb = ((const float4*)b2)[t];
            h2s[4 * t]     = a.x + bb.x;
            h2s[4 * t + 1] = a.y + bb.y;
            h2s[4 * t + 2] = a.z + bb.z;
            h2s[4 * t + 3] = a.w + bb.w;
        }
        __syncthreads();
    }

    // ---- f[128] = relu(h2 @ fc1W[256,128] + fc1b) : float2, 8-way
    {
        const float2* Wp = (const float2*)fc1W;    // [256][64]
        const int k0 = oc * 32, k1 = k0 + 32;
        float2 acc = {0.f, 0.f};
        #pragma unroll 8
        for (int k = k0; k < k1; ++k) {
            float s = h2s[k];
            float2 w = Wp[k * 64 + lane];
            acc.x += s * w.x; acc.y += s * w.y;
        }
        part2[oc][lane] = acc;
        __syncthreads();
        if (t < 64) {
            float2 a = part2[0][t];
            #pragma unroll
            for (int j = 1; j < 8; ++j) { a.x += part2[j][t].x; a.y += part2[j][t].y; }
            fsh[2 * t]     = fmaxf(a.x + fc1b[2 * t], 0.f);
            fsh[2 * t + 1] = fmaxf(a.y + fc1b[2 * t + 1], 0.f);
        }
        __syncthreads();
    }

    // ---- o = f . fc2_W + fc2_b ; write outputs
    {
        float p = (t < G_ / 2) ? fsh[t] * fc2W[t] : 0.f;
        #pragma unroll
        for (int off = 32; off > 0; off >>= 1) p += __shfl_down(p, off, 64);
        if (lane == 0) red[oc] = p;
        __syncthreads();
        if (t == 0) {
            float o = fc2b[0];
            #pragma unroll
            for (int j = 0; j < 8; ++j) o += red[j];
            oval = o;
        }
        __syncthreads();
        const float o = oval;
        const float sig = 1.0f / (1.0f + expf(-o));
        if (t < B_)            outp[t] = sig;   // output 0: sigmoid(o)
        else if (t < 2 * B_)   outp[t] = o;     // output 1: o
    }
}

// ---------------------------------------------------------------------------
extern "C" void kernel_launch(void* const* d_in, const int* in_sizes, int n_in,
                              void* d_out, int out_size, void* d_ws, size_t ws_size,
                              hipStream_t stream) {
    const int* meds  = (const int*)d_in[0];
    const int* chart = (const int*)d_in[1];
    const int* outv  = (const int*)d_in[2];
    const int* proc  = (const int*)d_in[3];
    const int* lab   = (const int*)d_in[4];
    const int* conds = (const int*)d_in[5];
    const int* demo  = (const int*)d_in[6];
    const float* medE   = (const float*)d_in[7];
    const float* chartE = (const float*)d_in[8];
    const float* outE   = (const float*)d_in[9];
    const float* procE  = (const float*)d_in[10];
    const float* labE   = (const float*)d_in[11];
    const float* condE  = (const float*)d_in[12];
    const float* genE   = (const float*)d_in[13];
    const float* ethE   = (const float*)d_in[14];
    const float* insE   = (const float*)d_in[15];
    const float* ageE   = (const float*)d_in[16];
    const float* projW  = (const float*)d_in[17];
    const float* projb  = (const float*)d_in[18];
    const float* W1     = (const float*)d_in[19];
    const float* b1     = (const float*)d_in[20];
    const float* W2     = (const float*)d_in[21];
    const float* b2     = (const float*)d_in[22];
    const float* fc1W   = (const float*)d_in[23];
    const float* fc1b   = (const float*)d_in[24];
    const float* fc2W   = (const float*)d_in[25];
    const float* fc2b   = (const float*)d_in[26];

    float* rm   = (float*)d_ws;          // 8817 floats
    float* macc = rm + OFF_MACC;         // 435 floats
    float* outp = (float*)d_out;         // 128 floats

    // A: row means — one wave per row, 4 waves/block
    int blocksA = (TOTROWS_ + 3) / 4;
    rowmeans_kernel<<<blocksA, 256, 0, stream>>>(
        medE, chartE, outE, procE, labE, condE, genE, ethE, insE, ageE, rm);

    // B: column gather-sums — one block per column
    colsum_kernel<<<TOTK_, 256, 0, stream>>>(
        meds, chart, outv, proc, lab, conds, demo, rm, macc);

    // C: MLP head — single block, 512 threads, deep-MLP pipeline
    head_kernel<<<1, 512, 0, stream>>>(
        macc, projW, projb, W1, b1, W2, b2, fc1W, fc1b, fc2W, fc2b, outp);
}